// Round 13
// baseline (226.138 us; speedup 1.0000x reference)
//
#include <hip/hip_runtime.h>
#include <math.h>

// Problem constants (fixed by reference): B=4, S=2048, D=512, H=8, R=8, dk=64
#define B_ 4
#define S_ 2048
#define D_ 512
#define H_ 8
#define R_ 8
#define DK_ 64
#define EPB   (2*R_*S_)         // 32768 edges per (b,h)
#define ELLCAP 64               // max in-degree slots; Poisson(15) tail ~2e-8

typedef __attribute__((ext_vector_type(8))) short bf16x8;
typedef __attribute__((ext_vector_type(8))) unsigned short ushort8_t;
typedef __attribute__((ext_vector_type(4))) float f32x4;

__device__ inline unsigned short f2bf(float f) {
    unsigned u = __builtin_bit_cast(unsigned, f);
    u += 0x7fffu + ((u >> 16) & 1u);   // RNE (no NaN inputs here)
    return (unsigned short)(u >> 16);
}
__device__ inline float bf2f(unsigned short u) {
    return __builtin_bit_cast(float, ((unsigned)u) << 16);
}

// ---------------- prep ------------------------------------------------------
// Fragment order (16x16x32 MFMA, HW-verified layouts): element (row, k) of a
// row-major [rows x 512] matrix lives at
//   F[(( (row>>4)*16 + (k>>5) )*64 + (row&15) + 16*((k>>3)&3))*8 + (k&7)]
// so a wave's A/B fragment load is ONE coalesced 1 KB global_load_dwordx4 at
// base + lane*16. blocks 0..6143: q/k/v -> A' frag order (2048 each);
// 6144..6655: W -> W' frag order (128 each); 6656..6679: rel cvt.
__global__ __launch_bounds__(256) void prep(
    const float* __restrict__ query, const float* __restrict__ key,
    const float* __restrict__ value,
    const float* __restrict__ Wq, const float* __restrict__ Wk,
    const float* __restrict__ Wv, const float* __restrict__ Wo,
    const float* __restrict__ rel_q, const float* __restrict__ rel_k,
    const float* __restrict__ rel_v,
    unsigned short* __restrict__ aq, unsigned short* __restrict__ ak,
    unsigned short* __restrict__ av,
    unsigned short* __restrict__ wqp, unsigned short* __restrict__ wkp,
    unsigned short* __restrict__ wvp, unsigned short* __restrict__ wop,
    unsigned short* __restrict__ rqb, unsigned short* __restrict__ rkb,
    unsigned short* __restrict__ rvb)
{
    int bid = blockIdx.x;
    int t = threadIdx.x;
    if (bid < 6656) {
        const float* x;
        unsigned short* y;
        int fi;
        if (bid < 6144) {
            int z = bid >> 11;             // 0..2
            x = (z == 0) ? query : (z == 1) ? key : value;
            y = (z == 0) ? aq : (z == 1) ? ak : av;
            fi = (bid & 2047) * 256 + t;   // 0..524287
        } else {
            int r = bid - 6144;            // 0..511
            int z = r >> 7;                // 0..3
            x = (z == 0) ? Wq : (z == 1) ? Wk : (z == 2) ? Wv : Wo;
            y = (z == 0) ? wqp : (z == 1) ? wkp : (z == 2) ? wvp : wop;
            fi = (r & 127) * 256 + t;      // 0..32767
        }
        int lane = fi & 63;
        int mg   = fi >> 10;               // row group (row>>4)
        int kc   = (fi >> 6) & 15;         // k chunk (k>>5)
        int row  = mg * 16 + (lane & 15);
        int col  = kc * 32 + ((lane >> 4) << 3);
        const float* src = x + (size_t)row * D_ + col;
        float4 a0 = *(const float4*)src;
        float4 a1 = *(const float4*)(src + 4);
        ushort8_t c;
        c[0] = f2bf(a0.x); c[1] = f2bf(a0.y); c[2] = f2bf(a0.z); c[3] = f2bf(a0.w);
        c[4] = f2bf(a1.x); c[5] = f2bf(a1.y); c[6] = f2bf(a1.z); c[7] = f2bf(a1.w);
        *(ushort8_t*)&y[(size_t)fi * 8] = c;
    } else {
        int rr = bid - 6656;               // 0..23
        int z = rr >> 3;                   // 0..2
        const float* x = (z == 0) ? rel_q : (z == 1) ? rel_k : rel_v;
        unsigned short* y = (z == 0) ? rqb : (z == 1) ? rkb : rvb;
        size_t i = ((size_t)(rr & 7) * 256 + t) * 4;
        float4 v = *(const float4*)&x[i];
        *(ushort4*)&y[i] = make_ushort4(f2bf(v.x), f2bf(v.y), f2bf(v.z), f2bf(v.w));
    }
}

// ---------------- QKV GEMM: BARRIER-FREE, LDS-FREE --------------------------
// A' and W' both in fragment order -> every operand is one coalesced 1 KB
// wave load from L2; no __syncthreads, no vmcnt(0) drain; compiler pipelines
// load->MFMA with fine-grained vmcnt. 128x128 tile, 4 waves 2x2, 4x4 frags.
// 1-D grid, XCD m-grouping: A m-strip HBM-fetched once, reused from L2.
__global__ __launch_bounds__(256) void gemm_qkv(
    const unsigned short* __restrict__ A0, const unsigned short* __restrict__ A1,
    const unsigned short* __restrict__ A2,
    const unsigned short* __restrict__ W0, const unsigned short* __restrict__ W1,
    const unsigned short* __restrict__ W2,
    const float* __restrict__ bi0, const float* __restrict__ bi1, const float* __restrict__ bi2,
    unsigned short* __restrict__ C0, unsigned short* __restrict__ C1,
    unsigned short* __restrict__ C2)
{
    const int bi  = blockIdx.x;           // 768
    const int xcd = bi & 7;
    const int r   = bi >> 3;              // 0..95
    const int z   = r >> 5;               // 0..2
    const int rr  = r & 31;
    const int mg0 = (xcd * 8 + (rr >> 2)) * 8;   // 128 rows = 8 mg
    const int ng0 = (rr & 3) * 8;                // 128 cols = 8 ng

    const unsigned short* A = (z == 0) ? A0 : (z == 1) ? A1 : A2;
    const unsigned short* W = (z == 0) ? W0 : (z == 1) ? W1 : W2;
    const float* bias       = (z == 0) ? bi0 : (z == 1) ? bi1 : bi2;
    unsigned short* C       = (z == 0) ? C0 : (z == 1) ? C1 : C2;

    const int t    = threadIdx.x;
    const int lane = t & 63;
    const int w    = t >> 6;
    const int wm   = w >> 1, wn = w & 1;

    f32x4 acc[4][4] = {};

    #pragma unroll 2
    for (int kc = 0; kc < 16; ++kc) {
        bf16x8 af[4], bfr[4];
        #pragma unroll
        for (int fm = 0; fm < 4; ++fm) {
            int mg = mg0 + wm * 4 + fm;
            af[fm] = *(const bf16x8*)&A[(size_t)(((mg * 16 + kc) << 6) + lane) * 8];
        }
        #pragma unroll
        for (int fn = 0; fn < 4; ++fn) {
            int ng = ng0 + wn * 4 + fn;
            bfr[fn] = *(const bf16x8*)&W[(size_t)(((ng * 16 + kc) << 6) + lane) * 8];
        }
        #pragma unroll
        for (int fm = 0; fm < 4; ++fm)
            #pragma unroll
            for (int fn = 0; fn < 4; ++fn)
                acc[fm][fn] = __builtin_amdgcn_mfma_f32_16x16x32_bf16(af[fm], bfr[fn], acc[fm][fn], 0, 0, 0);
    }

    // epilogue: C/D layout col = lane&15, row = (lane>>4)*4 + reg -> bhsd bf16
    #pragma unroll
    for (int fm = 0; fm < 4; ++fm) {
        #pragma unroll
        for (int fn = 0; fn < 4; ++fn) {
            #pragma unroll
            for (int rg = 0; rg < 4; ++rg) {
                int m = (mg0 + wm * 4 + fm) * 16 + (lane >> 4) * 4 + rg;
                int n = (ng0 + wn * 4 + fn) * 16 + (lane & 15);
                float val = acc[fm][fn][rg] + bias[n];
                int b = m >> 11, s = m & (S_ - 1);
                int h = n >> 6,  d = n & 63;
                C[((((size_t)b * H_ + h) * S_ + s) << 6) + d] = f2bf(val);
            }
        }
    }
}

// ---------------- output GEMM: BARRIER-FREE, LDS-FREE -----------------------
// A'' (attn, written in frag order by attn_fused) and W' direct-to-reg.
// 128x64 tile, 4 waves 2x2 (64m x 32n per wave), fp32 row-major out.
__global__ __launch_bounds__(256) void gemm_out(
    const unsigned short* __restrict__ A, const unsigned short* __restrict__ W,
    const float* __restrict__ bias, float* __restrict__ Cf)
{
    const int bi  = blockIdx.x;           // 512
    const int xcd = bi & 7;
    const int r   = bi >> 3;              // 0..63
    const int mg0 = (xcd * 8 + (r >> 3)) * 8;
    const int ng0 = (r & 7) * 4;

    const int t    = threadIdx.x;
    const int lane = t & 63;
    const int w    = t >> 6;
    const int wm   = w >> 1, wn = w & 1;

    f32x4 acc[4][2] = {};

    #pragma unroll 2
    for (int kc = 0; kc < 16; ++kc) {
        bf16x8 af[4], bfr[2];
        #pragma unroll
        for (int fm = 0; fm < 4; ++fm) {
            int mg = mg0 + wm * 4 + fm;
            af[fm] = *(const bf16x8*)&A[(size_t)(((mg * 16 + kc) << 6) + lane) * 8];
        }
        #pragma unroll
        for (int fn = 0; fn < 2; ++fn) {
            int ng = ng0 + wn * 2 + fn;
            bfr[fn] = *(const bf16x8*)&W[(size_t)(((ng * 16 + kc) << 6) + lane) * 8];
        }
        #pragma unroll
        for (int fm = 0; fm < 4; ++fm)
            #pragma unroll
            for (int fn = 0; fn < 2; ++fn)
                acc[fm][fn] = __builtin_amdgcn_mfma_f32_16x16x32_bf16(af[fm], bfr[fn], acc[fm][fn], 0, 0, 0);
    }

    #pragma unroll
    for (int fm = 0; fm < 4; ++fm) {
        #pragma unroll
        for (int fn = 0; fn < 2; ++fn) {
            #pragma unroll
            for (int rg = 0; rg < 4; ++rg) {
                int m = (mg0 + wm * 4 + fm) * 16 + (lane >> 4) * 4 + rg;
                int n = (ng0 + wn * 2 + fn) * 16 + (lane & 15);
                Cf[(size_t)m * D_ + n] = acc[fm][fn][rg] + bias[n];
            }
        }
    }
}

// ---------------- fused ELL-build + score+softmax+aggregate -----------------
// R10/R12-proven kernel; ONLY change: output written in fragment order so
// gemm_out can read it barrier-free. Element (m = b*2048+dst, k = h*64+d):
// frag addr = (((m>>4)*16 + (k>>5))*64 + (m&15) + 16*((k>>3)&3))*8 + (k&7);
// for our ushort8 chunk: kc = h*2 + (sub>>2), ln = (m&15) + ((sub&3)<<4).
__global__ __launch_bounds__(1024) void attn_fused(
    const unsigned short* __restrict__ q, const unsigned short* __restrict__ k_,
    const unsigned short* __restrict__ v_,
    const unsigned short* __restrict__ rel_q, const unsigned short* __restrict__ rel_k,
    const unsigned short* __restrict__ rel_v,
    const int* __restrict__ start_nodes, const int* __restrict__ end_nodes,
    unsigned short* __restrict__ attn)
{
    __shared__ unsigned short ell[128 * ELLCAP];   // 16 KB
    __shared__ int cnt[128];
    const int bi  = blockIdx.x;          // 512 blocks
    const int xcd = bi & 7;
    const int loc = bi >> 3;             // 0..63
    const int bh  = xcd * 4 + (loc >> 4);
    const int dlo = (loc & 15) << 7;     // 128-dst window base
    const int t   = threadIdx.x;

    if (t < 128) cnt[t] = 0;
    __syncthreads();

    // ---- scan phase ----
    const int base_idx = bh * (R_ * S_);
    for (int f = t; f < EPB; f += 1024) {   // 32 iterations
        int r2 = f >> 11;
        if (r2 == 0) continue;              // first-S flat entries masked
        int s = f & (S_ - 1);
        int idx = base_idx + (r2 & 7) * S_ + s;
        int sn = start_nodes[idx];
        if (sn == -1) continue;             // padded edge
        int en = end_nodes[idx];
        int dst = (r2 < R_) ? en : sn;
        unsigned rel = (unsigned)(dst - dlo);
        if (rel < 128u) {
            int ki = (r2 < R_) ? sn : en;
            int pos = atomicAdd(&cnt[rel], 1);
            if (pos < ELLCAP)
                ell[(rel << 6) + pos] = (unsigned short)((r2 << 11) | ki);
        }
    }
    __syncthreads();

    // ---- gather phase ----
    const int w    = t >> 6;
    const int lane = t & 63;
    const int grp  = lane >> 3;          // edge slot within group-of-8
    const int sub  = lane & 7;           // dk chunk (8 elems)
    const int h    = bh & 7;
    const size_t node_base = ((size_t)bh << 11);

    for (int dd = 0; dd < 8; ++dd) {
        int dl  = dd * 16 + w;           // 0..127
        int dst = dlo + dl;

        ushort8_t q8 = *(const ushort8_t*)&q[((node_base + dst) << 6) + sub * 8];
        float qv[8];
        #pragma unroll
        for (int i = 0; i < 8; ++i) qv[i] = bf2f(q8[i]);

        int n = cnt[dl];
        if (n > ELLCAP) n = ELLCAP;
        int d_all = (int)ell[(dl << 6) + lane];

        float den = 0.f;
        float o[8] = {};
        #pragma unroll 2
        for (int j = 0; j < n; j += 8) {
            int slot = j + grp;
            int d = __shfl(d_all, slot);
            bool valid = slot < n;
            int ki = d & (S_ - 1);
            int r2 = (d >> 11) & 15;
            ushort8_t k8  = *(const ushort8_t*)&k_  [((node_base + ki) << 6) + sub * 8];
            ushort8_t rk8 = *(const ushort8_t*)&rel_k[(((h << 4) + r2) << 6) + sub * 8];
            ushort8_t rq8 = *(const ushort8_t*)&rel_q[(((h << 4) + r2) << 6) + sub * 8];
            float p = 0.f;
            #pragma unroll
            for (int i = 0; i < 8; ++i)
                p = fmaf(bf2f(k8[i]), qv[i] + bf2f(rq8[i]),
                         fmaf(qv[i], bf2f(rk8[i]), p));
            p += __shfl_xor(p, 1);
            p += __shfl_xor(p, 2);
            p += __shfl_xor(p, 4);
            float sf = valid ? __expf(p * (1.0f / 24.0f)) : 0.f;   // 3*sqrt(64)=24
            ushort8_t v8  = *(const ushort8_t*)&v_  [((node_base + ki) << 6) + sub * 8];
            ushort8_t rv8 = *(const ushort8_t*)&rel_v[(((h << 4) + r2) << 6) + sub * 8];
            den += sf;
            #pragma unroll
            for (int i = 0; i < 8; ++i)
                o[i] = fmaf(sf, bf2f(v8[i]) + bf2f(rv8[i]), o[i]);
        }
        den += __shfl_xor(den, 8); den += __shfl_xor(den, 16); den += __shfl_xor(den, 32);
        #pragma unroll
        for (int i = 0; i < 8; ++i) {
            o[i] += __shfl_xor(o[i], 8);
            o[i] += __shfl_xor(o[i], 16);
            o[i] += __shfl_xor(o[i], 32);
        }
        if (grp == 0) {
            float inv = (den > 0.f) ? 1.0f / den : 0.f;
            ushort8_t rs;
            #pragma unroll
            for (int i = 0; i < 8; ++i) rs[i] = f2bf(o[i] * inv);
            int m  = ((bh >> 3) << 11) + dst;          // b*2048 + dst
            int kc = (h << 1) + (sub >> 2);
            int ln = (m & 15) + ((sub & 3) << 4);
            *(ushort8_t*)&attn[(size_t)((((m >> 4) * 16 + kc) << 6) + ln) * 8] = rs;
        }
    }
}

extern "C" void kernel_launch(void* const* d_in, const int* in_sizes, int n_in,
                              void* d_out, int out_size, void* d_ws, size_t ws_size,
                              hipStream_t stream) {
    const float* query = (const float*)d_in[0];
    const float* key   = (const float*)d_in[1];
    const float* value = (const float*)d_in[2];
    const int* start_nodes = (const int*)d_in[3];
    const int* end_nodes   = (const int*)d_in[4];
    const float* rel_q = (const float*)d_in[5];
    const float* rel_k = (const float*)d_in[6];
    const float* rel_v = (const float*)d_in[7];
    const float* Wq = (const float*)d_in[8];
    const float* bq = (const float*)d_in[9];
    const float* Wk = (const float*)d_in[10];
    const float* bk = (const float*)d_in[11];
    const float* Wv = (const float*)d_in[12];
    const float* bv = (const float*)d_in[13];
    const float* Wo = (const float*)d_in[14];
    const float* bo = (const float*)d_in[15];
    float* out = (float*)d_out;

    const size_t NQ = (size_t)B_ * H_ * S_ * DK_;   // 4,194,304
    const size_t NW = (size_t)D_ * D_;              // 262,144
    const size_t NR = (size_t)H_ * 2 * R_ * DK_;    // 8,192
    unsigned short* p = (unsigned short*)d_ws;
    unsigned short* aq = p;            p += NQ;   // inputs, fragment order
    unsigned short* ak = p;            p += NQ;
    unsigned short* av = p;            p += NQ;
    unsigned short* q  = p;            p += NQ;   // projections bf16 [B,H,S,dk]
    unsigned short* k  = p;            p += NQ;
    unsigned short* v  = p;            p += NQ;
    unsigned short* attn = p;          p += NQ;   // attn output, fragment order
    unsigned short* wqp = p;           p += NW;   // W fragment layouts
    unsigned short* wkp = p;           p += NW;
    unsigned short* wvp = p;           p += NW;
    unsigned short* wop = p;           p += NW;
    unsigned short* rqb = p;           p += NR;
    unsigned short* rkb = p;           p += NR;
    unsigned short* rvb = p;           p += NR;

    // 1) fused converts + fragment swizzles (one dispatch)
    prep<<<6680, 256, 0, stream>>>(query, key, value, Wq, Wk, Wv, Wo,
                                   rel_q, rel_k, rel_v,
                                   aq, ak, av, wqp, wkp, wvp, wop,
                                   rqb, rkb, rvb);

    // 2) fused QKV projection (barrier-free, LDS-free)
    gemm_qkv<<<768, 256, 0, stream>>>(aq, ak, av, wqp, wkp, wvp,
                                      bq, bk, bv, q, k, v);

    // 3) fused ELL-build + attention (writes attn in fragment order)
    attn_fused<<<512, 1024, 0, stream>>>(q, k, v, rqb, rkb, rvb,
                                         start_nodes, end_nodes, attn);

    // 4) output projection (barrier-free, LDS-free, fp32 out)
    gemm_out<<<512, 256, 0, stream>>>(attn, wop, bo, out);
}

// Round 14
// 222.930 us; speedup vs baseline: 1.0144x; 1.0144x over previous
//
#include <hip/hip_runtime.h>
#include <math.h>

// Problem constants (fixed by reference): B=4, S=2048, D=512, H=8, R=8, dk=64
#define B_ 4
#define S_ 2048
#define D_ 512
#define H_ 8
#define R_ 8
#define DK_ 64
#define EPB   (2*R_*S_)         // 32768 edges per (b,h)
#define ELLCAP 64               // max in-degree slots; Poisson(15) tail ~2e-8

typedef __attribute__((ext_vector_type(8))) short bf16x8;
typedef __attribute__((ext_vector_type(8))) unsigned short ushort8_t;
typedef __attribute__((ext_vector_type(4))) float f32x4;

__device__ inline unsigned short f2bf(float f) {
    unsigned u = __builtin_bit_cast(unsigned, f);
    u += 0x7fffu + ((u >> 16) & 1u);   // RNE (no NaN inputs here)
    return (unsigned short)(u >> 16);
}
__device__ inline float bf2f(unsigned short u) {
    return __builtin_bit_cast(float, ((unsigned)u) << 16);
}

// ---------------- dispatch 1: fused QKV GEMM + rel cvt + Wo frag-swizzle ----
// bid < 768:  GEMM C[m,n] = A[m,k]*W[n,k] + bias, raw fp32 A and W with
//             inline bf16 cvt + LDS staging (R10-proven XOR chunk swizzle:
//             LDS slot s of row r holds global chunk s^(r&7); read side
//             cp = (c0 + (lane>>4)) ^ (lane&7)). C bf16 [B,H,S,dk].
//             1-D grid, XCD m-grouping for A L2 reuse.
// bid 768..791:  rel_q/rel_k/rel_v fp32 -> bf16 (24 blocks).
// bid 792..919:  Wo -> frag-order W' bf16 (consumed by gemm_out next
//                dispatch; no intra-dispatch consumer -> no race).
__global__ __launch_bounds__(256) void gemm_qkv_fused(
    const float* __restrict__ A0, const float* __restrict__ A1,
    const float* __restrict__ A2,
    const float* __restrict__ W0, const float* __restrict__ W1,
    const float* __restrict__ W2, const float* __restrict__ Wo,
    const float* __restrict__ bi0, const float* __restrict__ bi1, const float* __restrict__ bi2,
    const float* __restrict__ rel_q, const float* __restrict__ rel_k,
    const float* __restrict__ rel_v,
    unsigned short* __restrict__ C0, unsigned short* __restrict__ C1,
    unsigned short* __restrict__ C2,
    unsigned short* __restrict__ wop,
    unsigned short* __restrict__ rqb, unsigned short* __restrict__ rkb,
    unsigned short* __restrict__ rvb)
{
    const int bid = blockIdx.x;
    const int t   = threadIdx.x;

    if (bid >= 768) {
        if (bid < 792) {
            int rr = bid - 768;            // 0..23
            int z = rr >> 3;               // 0..2
            const float* x = (z == 0) ? rel_q : (z == 1) ? rel_k : rel_v;
            unsigned short* y = (z == 0) ? rqb : (z == 1) ? rkb : rvb;
            size_t i = ((size_t)(rr & 7) * 256 + t) * 4;
            float4 v = *(const float4*)&x[i];
            *(ushort4*)&y[i] = make_ushort4(f2bf(v.x), f2bf(v.y), f2bf(v.z), f2bf(v.w));
        } else {
            // Wo -> fragment order: F[((ng*16+kc)*64 + lane)*8 + j]
            //   = Wo[(ng*16 + (lane&15))*512 + kc*32 + (lane>>4)*8 + j]
            int fi = (bid - 792) * 256 + t;    // 0..32767
            int lane = fi & 63;
            int ng   = fi >> 10;
            int kc   = (fi >> 6) & 15;
            const float* src = Wo + (size_t)(ng * 16 + (lane & 15)) * D_
                                  + kc * 32 + ((lane >> 4) << 3);
            float4 a0 = *(const float4*)src;
            float4 a1 = *(const float4*)(src + 4);
            ushort8_t c;
            c[0] = f2bf(a0.x); c[1] = f2bf(a0.y); c[2] = f2bf(a0.z); c[3] = f2bf(a0.w);
            c[4] = f2bf(a1.x); c[5] = f2bf(a1.y); c[6] = f2bf(a1.z); c[7] = f2bf(a1.w);
            *(ushort8_t*)&wop[(size_t)fi * 8] = c;
        }
        return;
    }

    __shared__ unsigned short As[128 * 64];
    __shared__ unsigned short Ws[128 * 64];
    const int xcd = bid & 7;
    const int r   = bid >> 3;             // 0..95
    const int z   = r >> 5;               // 0..2
    const int rr  = r & 31;
    const int m0  = (xcd * 8 + (rr >> 2)) * 128;
    const int n0  = (rr & 3) * 128;

    const float* A    = (z == 0) ? A0 : (z == 1) ? A1 : A2;
    const float* W    = (z == 0) ? W0 : (z == 1) ? W1 : W2;
    const float* bias = (z == 0) ? bi0 : (z == 1) ? bi1 : bi2;
    unsigned short* C = (z == 0) ? C0 : (z == 1) ? C1 : C2;

    const int lane = t & 63;
    const int w    = t >> 6;
    const int wm   = w >> 1, wn = w & 1;
    const int lr    = lane >> 3;           // row within 8-row stage chunk
    const int cglob = (lane & 7) ^ lr;     // swizzled global source chunk

    f32x4 acc[4][4] = {};

    for (int kk = 0; kk < D_; kk += 64) {
        // stage A and W tiles: fp32 load + cvt + ds_write_b128, XOR swizzle
        #pragma unroll
        for (int i = 0; i < 4; ++i) {
            int rowl = w * 32 + i * 8;
            {
                const float* ga = A + (size_t)(m0 + rowl + lr) * D_ + kk + cglob * 8;
                float4 a0 = *(const float4*)ga;
                float4 a1 = *(const float4*)(ga + 4);
                ushort8_t c;
                c[0] = f2bf(a0.x); c[1] = f2bf(a0.y); c[2] = f2bf(a0.z); c[3] = f2bf(a0.w);
                c[4] = f2bf(a1.x); c[5] = f2bf(a1.y); c[6] = f2bf(a1.z); c[7] = f2bf(a1.w);
                *(ushort8_t*)&As[(rowl + lr) * 64 + (lane & 7) * 8] = c;
            }
            {
                const float* gb = W + (size_t)(n0 + rowl + lr) * D_ + kk + cglob * 8;
                float4 b0 = *(const float4*)gb;
                float4 b1 = *(const float4*)(gb + 4);
                ushort8_t c;
                c[0] = f2bf(b0.x); c[1] = f2bf(b0.y); c[2] = f2bf(b0.z); c[3] = f2bf(b0.w);
                c[4] = f2bf(b1.x); c[5] = f2bf(b1.y); c[6] = f2bf(b1.z); c[7] = f2bf(b1.w);
                *(ushort8_t*)&Ws[(rowl + lr) * 64 + (lane & 7) * 8] = c;
            }
        }
        __syncthreads();

        #pragma unroll
        for (int ks = 0; ks < 64; ks += 32) {
            const int c0 = ks >> 3;            // 0 or 4
            bf16x8 af[4], bfr[4];
            #pragma unroll
            for (int mi = 0; mi < 4; ++mi) {
                int row = wm * 64 + mi * 16 + (lane & 15);
                int cp  = (c0 + (lane >> 4)) ^ (lane & 7);
                af[mi] = *(const bf16x8*)&As[row * 64 + cp * 8];
            }
            #pragma unroll
            for (int nj = 0; nj < 4; ++nj) {
                int row = wn * 64 + nj * 16 + (lane & 15);
                int cp  = (c0 + (lane >> 4)) ^ (lane & 7);
                bfr[nj] = *(const bf16x8*)&Ws[row * 64 + cp * 8];
            }
            #pragma unroll
            for (int mi = 0; mi < 4; ++mi)
                #pragma unroll
                for (int nj = 0; nj < 4; ++nj)
                    acc[mi][nj] = __builtin_amdgcn_mfma_f32_16x16x32_bf16(af[mi], bfr[nj], acc[mi][nj], 0, 0, 0);
        }
        __syncthreads();
    }

    // epilogue: C/D layout col = lane&15, row = (lane>>4)*4 + reg -> bhsd bf16
    #pragma unroll
    for (int mi = 0; mi < 4; ++mi) {
        #pragma unroll
        for (int nj = 0; nj < 4; ++nj) {
            #pragma unroll
            for (int rg = 0; rg < 4; ++rg) {
                int m = m0 + wm * 64 + mi * 16 + (lane >> 4) * 4 + rg;
                int n = n0 + wn * 64 + nj * 16 + (lane & 15);
                float val = acc[mi][nj][rg] + bias[n];
                int b = m >> 11, s = m & (S_ - 1);
                int h = n >> 6,  d = n & 63;
                C[((((size_t)b * H_ + h) * S_ + s) << 6) + d] = f2bf(val);
            }
        }
    }
}

// ---------------- dispatch 3: output GEMM, barrier-free, LDS-free -----------
// attn (frag order, from attn_fused) and Wo' (frag order) direct-to-reg.
// 128x64 tile, 4 waves 2x2 (64m x 32n per wave), fp32 row-major out.
__global__ __launch_bounds__(256) void gemm_out(
    const unsigned short* __restrict__ A, const unsigned short* __restrict__ W,
    const float* __restrict__ bias, float* __restrict__ Cf)
{
    const int bi  = blockIdx.x;           // 512
    const int xcd = bi & 7;
    const int r   = bi >> 3;              // 0..63
    const int mg0 = (xcd * 8 + (r >> 3)) * 8;
    const int ng0 = (r & 7) * 4;

    const int t    = threadIdx.x;
    const int lane = t & 63;
    const int w    = t >> 6;
    const int wm   = w >> 1, wn = w & 1;

    f32x4 acc[4][2] = {};

    #pragma unroll 2
    for (int kc = 0; kc < 16; ++kc) {
        bf16x8 af[4], bfr[2];
        #pragma unroll
        for (int fm = 0; fm < 4; ++fm) {
            int mg = mg0 + wm * 4 + fm;
            af[fm] = *(const bf16x8*)&A[(size_t)(((mg * 16 + kc) << 6) + lane) * 8];
        }
        #pragma unroll
        for (int fn = 0; fn < 2; ++fn) {
            int ng = ng0 + wn * 2 + fn;
            bfr[fn] = *(const bf16x8*)&W[(size_t)(((ng * 16 + kc) << 6) + lane) * 8];
        }
        #pragma unroll
        for (int fm = 0; fm < 4; ++fm)
            #pragma unroll
            for (int fn = 0; fn < 2; ++fn)
                acc[fm][fn] = __builtin_amdgcn_mfma_f32_16x16x32_bf16(af[fm], bfr[fn], acc[fm][fn], 0, 0, 0);
    }

    #pragma unroll
    for (int fm = 0; fm < 4; ++fm) {
        #pragma unroll
        for (int fn = 0; fn < 2; ++fn) {
            #pragma unroll
            for (int rg = 0; rg < 4; ++rg) {
                int m = (mg0 + wm * 4 + fm) * 16 + (lane >> 4) * 4 + rg;
                int n = (ng0 + wn * 2 + fn) * 16 + (lane & 15);
                Cf[(size_t)m * D_ + n] = acc[fm][fn][rg] + bias[n];
            }
        }
    }
}

// ---------------- dispatch 2: fused ELL-build + score+softmax+aggregate -----
// R13-proven kernel, unchanged. Output written in fragment order for the
// barrier-free gemm_out: for chunk (m = b*2048+dst, h, sub):
// kc = h*2 + (sub>>2), ln = (m&15) + ((sub&3)<<4).
__global__ __launch_bounds__(1024) void attn_fused(
    const unsigned short* __restrict__ q, const unsigned short* __restrict__ k_,
    const unsigned short* __restrict__ v_,
    const unsigned short* __restrict__ rel_q, const unsigned short* __restrict__ rel_k,
    const unsigned short* __restrict__ rel_v,
    const int* __restrict__ start_nodes, const int* __restrict__ end_nodes,
    unsigned short* __restrict__ attn)
{
    __shared__ unsigned short ell[128 * ELLCAP];   // 16 KB
    __shared__ int cnt[128];
    const int bi  = blockIdx.x;          // 512 blocks
    const int xcd = bi & 7;
    const int loc = bi >> 3;             // 0..63
    const int bh  = xcd * 4 + (loc >> 4);
    const int dlo = (loc & 15) << 7;     // 128-dst window base
    const int t   = threadIdx.x;

    if (t < 128) cnt[t] = 0;
    __syncthreads();

    // ---- scan phase ----
    const int base_idx = bh * (R_ * S_);
    for (int f = t; f < EPB; f += 1024) {   // 32 iterations
        int r2 = f >> 11;
        if (r2 == 0) continue;              // first-S flat entries masked
        int s = f & (S_ - 1);
        int idx = base_idx + (r2 & 7) * S_ + s;
        int sn = start_nodes[idx];
        if (sn == -1) continue;             // padded edge
        int en = end_nodes[idx];
        int dst = (r2 < R_) ? en : sn;
        unsigned rel = (unsigned)(dst - dlo);
        if (rel < 128u) {
            int ki = (r2 < R_) ? sn : en;
            int pos = atomicAdd(&cnt[rel], 1);
            if (pos < ELLCAP)
                ell[(rel << 6) + pos] = (unsigned short)((r2 << 11) | ki);
        }
    }
    __syncthreads();

    // ---- gather phase ----
    const int w    = t >> 6;
    const int lane = t & 63;
    const int grp  = lane >> 3;          // edge slot within group-of-8
    const int sub  = lane & 7;           // dk chunk (8 elems)
    const int h    = bh & 7;
    const size_t node_base = ((size_t)bh << 11);

    for (int dd = 0; dd < 8; ++dd) {
        int dl  = dd * 16 + w;           // 0..127
        int dst = dlo + dl;

        ushort8_t q8 = *(const ushort8_t*)&q[((node_base + dst) << 6) + sub * 8];
        float qv[8];
        #pragma unroll
        for (int i = 0; i < 8; ++i) qv[i] = bf2f(q8[i]);

        int n = cnt[dl];
        if (n > ELLCAP) n = ELLCAP;
        int d_all = (int)ell[(dl << 6) + lane];

        float den = 0.f;
        float o[8] = {};
        #pragma unroll 2
        for (int j = 0; j < n; j += 8) {
            int slot = j + grp;
            int d = __shfl(d_all, slot);
            bool valid = slot < n;
            int ki = d & (S_ - 1);
            int r2 = (d >> 11) & 15;
            ushort8_t k8  = *(const ushort8_t*)&k_  [((node_base + ki) << 6) + sub * 8];
            ushort8_t rk8 = *(const ushort8_t*)&rel_k[(((h << 4) + r2) << 6) + sub * 8];
            ushort8_t rq8 = *(const ushort8_t*)&rel_q[(((h << 4) + r2) << 6) + sub * 8];
            float p = 0.f;
            #pragma unroll
            for (int i = 0; i < 8; ++i)
                p = fmaf(bf2f(k8[i]), qv[i] + bf2f(rq8[i]),
                         fmaf(qv[i], bf2f(rk8[i]), p));
            p += __shfl_xor(p, 1);
            p += __shfl_xor(p, 2);
            p += __shfl_xor(p, 4);
            float sf = valid ? __expf(p * (1.0f / 24.0f)) : 0.f;   // 3*sqrt(64)=24
            ushort8_t v8  = *(const ushort8_t*)&v_  [((node_base + ki) << 6) + sub * 8];
            ushort8_t rv8 = *(const ushort8_t*)&rel_v[(((h << 4) + r2) << 6) + sub * 8];
            den += sf;
            #pragma unroll
            for (int i = 0; i < 8; ++i)
                o[i] = fmaf(sf, bf2f(v8[i]) + bf2f(rv8[i]), o[i]);
        }
        den += __shfl_xor(den, 8); den += __shfl_xor(den, 16); den += __shfl_xor(den, 32);
        #pragma unroll
        for (int i = 0; i < 8; ++i) {
            o[i] += __shfl_xor(o[i], 8);
            o[i] += __shfl_xor(o[i], 16);
            o[i] += __shfl_xor(o[i], 32);
        }
        if (grp == 0) {
            float inv = (den > 0.f) ? 1.0f / den : 0.f;
            ushort8_t rs;
            #pragma unroll
            for (int i = 0; i < 8; ++i) rs[i] = f2bf(o[i] * inv);
            int m  = ((bh >> 3) << 11) + dst;          // b*2048 + dst
            int kc = (h << 1) + (sub >> 2);
            int ln = (m & 15) + ((sub & 3) << 4);
            *(ushort8_t*)&attn[(size_t)((((m >> 4) * 16 + kc) << 6) + ln) * 8] = rs;
        }
    }
}

extern "C" void kernel_launch(void* const* d_in, const int* in_sizes, int n_in,
                              void* d_out, int out_size, void* d_ws, size_t ws_size,
                              hipStream_t stream) {
    const float* query = (const float*)d_in[0];
    const float* key   = (const float*)d_in[1];
    const float* value = (const float*)d_in[2];
    const int* start_nodes = (const int*)d_in[3];
    const int* end_nodes   = (const int*)d_in[4];
    const float* rel_q = (const float*)d_in[5];
    const float* rel_k = (const float*)d_in[6];
    const float* rel_v = (const float*)d_in[7];
    const float* Wq = (const float*)d_in[8];
    const float* bq = (const float*)d_in[9];
    const float* Wk = (const float*)d_in[10];
    const float* bk = (const float*)d_in[11];
    const float* Wv = (const float*)d_in[12];
    const float* bv = (const float*)d_in[13];
    const float* Wo = (const float*)d_in[14];
    const float* bo = (const float*)d_in[15];
    float* out = (float*)d_out;

    const size_t NQ = (size_t)B_ * H_ * S_ * DK_;   // 4,194,304
    const size_t NW = (size_t)D_ * D_;              // 262,144
    const size_t NR = (size_t)H_ * 2 * R_ * DK_;    // 8,192
    unsigned short* p = (unsigned short*)d_ws;
    unsigned short* q    = p;          p += NQ;   // projections bf16 [B,H,S,dk]
    unsigned short* k    = p;          p += NQ;
    unsigned short* v    = p;          p += NQ;
    unsigned short* attn = p;          p += NQ;   // attn output, fragment order
    unsigned short* wop  = p;          p += NW;   // Wo fragment layout
    unsigned short* rqb  = p;          p += NR;
    unsigned short* rkb  = p;          p += NR;
    unsigned short* rvb  = p;          p += NR;

    // 1) fused QKV projection (raw fp32 A+W, inline cvt) + rel cvt + Wo swizzle
    gemm_qkv_fused<<<920, 256, 0, stream>>>(
        query, key, value, Wq, Wk, Wv, Wo, bq, bk, bv,
        rel_q, rel_k, rel_v, q, k, v, wop, rqb, rkb, rvb);

    // 2) fused ELL-build + attention (writes attn in fragment order)
    attn_fused<<<512, 1024, 0, stream>>>(q, k, v, rqb, rkb, rvb,
                                         start_nodes, end_nodes, attn);

    // 3) output projection (barrier-free, LDS-free, fp32 out)
    gemm_out<<<512, 256, 0, stream>>>(attn, wop, bo, out);
}